// Round 1
// baseline (164.265 us; speedup 1.0000x reference)
//
#include <hip/hip_runtime.h>
#include <math.h>

#define NCLUS 56
#define HH 224
#define WW 224
#define BB 32
#define CELLS (NCLUS * NCLUS) /* 3136 */

// ---------------------------------------------------------------------------
// Kernel A: Sobel -> grad mag -> inverted -> 4x4 mean pool.
// One thread per pooled cell (32*3136 = 100352 threads). Reads only the edge
// channel (channel 64). Sign convention of the Sobel taps is irrelevant
// (squared), zero padding at borders.
// ---------------------------------------------------------------------------
__global__ void pool_kernel(const float* __restrict__ cf,
                            float* __restrict__ pooled) {
    int gid = blockIdx.x * blockDim.x + threadIdx.x;
    if (gid >= BB * CELLS) return;
    int b = gid / CELLS;
    int cell = gid - b * CELLS;
    int by = cell / NCLUS;
    int bx = cell - by * NCLUS;
    const float* e = cf + ((size_t)b * 65 + 64) * (HH * WW);

    int y0 = by * 4 - 1;
    int x0 = bx * 4 - 1;
    float patch[6][6];
#pragma unroll
    for (int i = 0; i < 6; ++i) {
        int y = y0 + i;
#pragma unroll
        for (int j = 0; j < 6; ++j) {
            int x = x0 + j;
            bool in = (y >= 0) && (y < HH) && (x >= 0) && (x < WW);
            patch[i][j] = in ? e[y * WW + x] : 0.0f;
        }
    }

    float s = 0.0f;
#pragma unroll
    for (int iy = 0; iy < 4; ++iy) {
#pragma unroll
        for (int ix = 0; ix < 4; ++ix) {
            float gx = (patch[iy][ix + 2] - patch[iy][ix])
                     + 2.0f * (patch[iy + 1][ix + 2] - patch[iy + 1][ix])
                     + (patch[iy + 2][ix + 2] - patch[iy + 2][ix]);
            float gy = (patch[iy + 2][ix] - patch[iy][ix])
                     + 2.0f * (patch[iy + 2][ix + 1] - patch[iy][ix + 1])
                     + (patch[iy + 2][ix + 2] - patch[iy][ix + 2]);
            float gm = sqrtf(gx * gx + gy * gy);
            s += 1.0f - 0.5f * gm;
        }
    }
    pooled[gid] = s * 0.0625f; // /16 exact
}

// ---------------------------------------------------------------------------
// Kernel B: per-batch top-56 (jax.lax.top_k semantics: descending value,
// ties -> lower index first) + build separable exp tables.
//   Ey layout [b][h][k]  (56 contiguous per (b,h) row for the output kernel)
//   Ex layout [b][k][w]  (coalesced across w per k)
// One block per batch, 256 threads. Key = sortable-uint(float) << 32 | ~idx,
// so u64 max gives max value with lower-index tie-break.
// ---------------------------------------------------------------------------
__global__ void topk_tables_kernel(const float* __restrict__ pooled,
                                   const float* __restrict__ stdp,
                                   float* __restrict__ Ey,
                                   float* __restrict__ Ex) {
    int b = blockIdx.x;
    int tid = threadIdx.x; // 256 threads = 4 waves
    __shared__ float vals[CELLS];
    __shared__ unsigned long long wk[4];
    __shared__ float sy_s[NCLUS], sx_s[NCLUS];

    for (int i = tid; i < CELLS; i += 256) vals[i] = pooled[b * CELLS + i];
    __syncthreads();

    for (int k = 0; k < NCLUS; ++k) {
        unsigned long long best = 0ull;
        for (int i = tid; i < CELLS; i += 256) {
            unsigned u = __float_as_uint(vals[i]);
            u = (u & 0x80000000u) ? ~u : (u | 0x80000000u);
            unsigned long long key =
                ((unsigned long long)u << 32) |
                (unsigned long long)(0xFFFFFFFFu - (unsigned)i);
            if (key > best) best = key;
        }
#pragma unroll
        for (int off = 32; off > 0; off >>= 1) {
            unsigned long long o = __shfl_down(best, off, 64);
            if (o > best) best = o;
        }
        if ((tid & 63) == 0) wk[tid >> 6] = best;
        __syncthreads();
        if (tid == 0) {
            unsigned long long m = wk[0];
            if (wk[1] > m) m = wk[1];
            if (wk[2] > m) m = wk[2];
            if (wk[3] > m) m = wk[3];
            int idx = (int)(0xFFFFFFFFu - (unsigned)(m & 0xFFFFFFFFull));
            sy_s[k] = (float)(idx / NCLUS) / (float)NCLUS;
            sx_s[k] = (float)(idx % NCLUS) / (float)NCLUS;
            vals[idx] = -INFINITY;
        }
        __syncthreads();
    }

    float stdv = stdp[0];
    for (int t = tid; t < NCLUS * HH; t += 256) {
        int k = t / HH;
        int i = t - k * HH;
        float coord = (float)i / 224.0f;
        float qy = (coord - sy_s[k]) / stdv;
        float qx = (coord - sx_s[k]) / stdv;
        Ey[((size_t)b * HH + i) * NCLUS + k] = expf(-(qy * qy));
        Ex[((size_t)b * NCLUS + k) * WW + i] = expf(-(qx * qx));
    }
}

// ---------------------------------------------------------------------------
// Kernel C: streaming softmax over K=56. One block per (b,h) row, lane = w.
// spatial_k = 0.5*(Ey[b,h,k] + Ex[b,k,w]); out = softmax_k(spatial).
// p[56] kept in registers (fully unrolled static indexing). Stores are
// coalesced 224-float rows per k. This kernel is HBM-write-bound.
// ---------------------------------------------------------------------------
__global__ __launch_bounds__(256) void markers_kernel(
        const float* __restrict__ Ey, const float* __restrict__ Ex,
        float* __restrict__ out) {
    int bh = blockIdx.x;
    int b = bh / HH;
    int h = bh - b * HH;
    __shared__ float ey[NCLUS];
    int tid = threadIdx.x;
    if (tid < NCLUS) ey[tid] = Ey[((size_t)b * HH + h) * NCLUS + tid];
    __syncthreads();
    if (tid >= WW) return;
    int w = tid;
    const float* exb = Ex + (size_t)b * NCLUS * WW;

    float p[NCLUS];
    float m = -INFINITY;
#pragma unroll
    for (int k = 0; k < NCLUS; ++k) {
        float s = 0.5f * (ey[k] + exb[k * WW + w]);
        p[k] = s;
        m = fmaxf(m, s);
    }
    float sum = 0.0f;
#pragma unroll
    for (int k = 0; k < NCLUS; ++k) {
        float e = __expf(p[k] - m);
        p[k] = e;
        sum += e;
    }
    float r = 1.0f / sum;
    size_t base = ((size_t)b * NCLUS * HH + h) * WW + w;
#pragma unroll
    for (int k = 0; k < NCLUS; ++k) {
        out[base + (size_t)k * (HH * WW)] = p[k] * r;
    }
}

// ---------------------------------------------------------------------------
extern "C" void kernel_launch(void* const* d_in, const int* in_sizes, int n_in,
                              void* d_out, int out_size, void* d_ws,
                              size_t ws_size, hipStream_t stream) {
    const float* cf = (const float*)d_in[0];   // (32, 65, 224, 224) f32
    const float* stdp = (const float*)d_in[1]; // scalar f32
    float* out = (float*)d_out;                // (32, 56, 224, 224) f32

    // workspace partition (needs ~3.7 MB total):
    //   pooled: 32*3136 f32            = 401,408 B
    //   Ey:     32*224*56 f32          = 1,605,632 B
    //   Ex:     32*56*224 f32          = 1,605,632 B
    char* ws = (char*)d_ws;
    float* pooled = (float*)ws;
    float* Ey = (float*)(ws + 512 * 1024);
    float* Ex = (float*)(ws + 512 * 1024 + 2 * 1024 * 1024);

    pool_kernel<<<(BB * CELLS + 255) / 256, 256, 0, stream>>>(cf, pooled);
    topk_tables_kernel<<<BB, 256, 0, stream>>>(pooled, stdp, Ey, Ex);
    markers_kernel<<<BB * HH, 256, 0, stream>>>(Ey, Ex, out);
}

// Round 2
// 159.697 us; speedup vs baseline: 1.0286x; 1.0286x over previous
//
#include <hip/hip_runtime.h>
#include <math.h>

#define NCLUS 56
#define HH 224
#define WW 224
#define BB 32
#define CELLS (NCLUS * NCLUS) /* 3136 */
#define HW (HH * WW)

// ---------------------------------------------------------------------------
// Kernel A: Sobel -> grad mag -> inverted -> 4x4 mean pool.
// One block per (batch, 4-row strip of pooled cells). Edge rows staged in LDS
// with coalesced loads (18 rows x 226 cols, zero-padded borders), then 224
// threads each compute one pooled cell (identical arithmetic order to ref).
// ---------------------------------------------------------------------------
__global__ __launch_bounds__(256) void pool_kernel(const float* __restrict__ cf,
                                                   float* __restrict__ pooled) {
    __shared__ float lds[18][226];
    int b = blockIdx.x / 14;
    int grp = blockIdx.x - b * 14; // 14 strips of 4 cell-rows
    int tid = threadIdx.x;
    const float* e = cf + ((size_t)b * 65 + 64) * HW;

    int y0 = grp * 16 - 1; // first image row staged (may be -1)
    for (int t = tid; t < 18 * 224; t += 256) {
        int r = t / 224;
        int c = t - r * 224;
        int y = y0 + r;
        lds[r][c + 1] = (y >= 0 && y < HH) ? e[y * WW + c] : 0.0f;
    }
    if (tid < 18) { lds[tid][0] = 0.0f; lds[tid][225] = 0.0f; }
    __syncthreads();

    if (tid >= 224) return;
    int lby = tid / 56;
    int bx = tid - lby * 56;
    int r0 = lby * 4;  // LDS row of patch top (= image row gby*4-1)
    int c0 = bx * 4;   // LDS col of patch left (= image col bx*4-1)

    float patch[6][6];
#pragma unroll
    for (int i = 0; i < 6; ++i)
#pragma unroll
        for (int j = 0; j < 6; ++j) patch[i][j] = lds[r0 + i][c0 + j];

    float s = 0.0f;
#pragma unroll
    for (int iy = 0; iy < 4; ++iy) {
#pragma unroll
        for (int ix = 0; ix < 4; ++ix) {
            float gx = (patch[iy][ix + 2] - patch[iy][ix])
                     + 2.0f * (patch[iy + 1][ix + 2] - patch[iy + 1][ix])
                     + (patch[iy + 2][ix + 2] - patch[iy + 2][ix]);
            float gy = (patch[iy + 2][ix] - patch[iy][ix])
                     + 2.0f * (patch[iy + 2][ix + 1] - patch[iy][ix + 1])
                     + (patch[iy + 2][ix + 2] - patch[iy][ix + 2]);
            float gm = sqrtf(gx * gx + gy * gy);
            s += 1.0f - 0.5f * gm;
        }
    }
    pooled[b * CELLS + (grp * 4 + lby) * NCLUS + bx] = s * 0.0625f;
}

// ---------------------------------------------------------------------------
// Kernel B: per-batch top-56 + exp-factored tables.
// Wave 0 holds all 3136 keys in registers (49 u64/lane). Since keys are
// unique (idx packed in low bits, inverted so lower idx = larger key), the
// k-th selection is "max key strictly < previous winner" -- no invalidation,
// no LDS, no barriers in the serial loop. Waves 1-3 wait, then all 256
// threads generate Fy = exp(0.5*exp(-(dy/std)^2)) and Fx likewise, so the
// output kernel needs only products (softmax is shift/scale-invariant).
// ---------------------------------------------------------------------------
__global__ __launch_bounds__(256) void topk_tables_kernel(
        const float* __restrict__ pooled, const float* __restrict__ stdp,
        float* __restrict__ Fy, float* __restrict__ Fx) {
    int b = blockIdx.x;
    int tid = threadIdx.x;
    __shared__ float sy_s[NCLUS], sx_s[NCLUS];

    if (tid < 64) {
        unsigned long long key[49];
#pragma unroll
        for (int j = 0; j < 49; ++j) {
            int i = j * 64 + tid;
            unsigned u = __float_as_uint(pooled[b * CELLS + i]);
            u = (u & 0x80000000u) ? ~u : (u | 0x80000000u);
            key[j] = ((unsigned long long)u << 32) |
                     (unsigned long long)(0xFFFFFFFFu - (unsigned)i);
        }
        unsigned long long prev = ~0ull;
        for (int k = 0; k < NCLUS; ++k) {
            unsigned long long b0 = 0, b1 = 0, b2 = 0, b3 = 0;
#pragma unroll
            for (int j = 0; j < 48; j += 4) {
                unsigned long long m0 = (key[j] < prev) ? key[j] : 0ull;
                unsigned long long m1 = (key[j + 1] < prev) ? key[j + 1] : 0ull;
                unsigned long long m2 = (key[j + 2] < prev) ? key[j + 2] : 0ull;
                unsigned long long m3 = (key[j + 3] < prev) ? key[j + 3] : 0ull;
                if (m0 > b0) b0 = m0;
                if (m1 > b1) b1 = m1;
                if (m2 > b2) b2 = m2;
                if (m3 > b3) b3 = m3;
            }
            unsigned long long ml = (key[48] < prev) ? key[48] : 0ull;
            if (ml > b0) b0 = ml;
            if (b1 > b0) b0 = b1;
            if (b3 > b2) b2 = b3;
            unsigned long long best = (b2 > b0) ? b2 : b0;
#pragma unroll
            for (int off = 32; off >= 1; off >>= 1) {
                unsigned long long o = __shfl_xor(best, off, 64);
                if (o > best) best = o;
            }
            prev = best;
            if (tid == 0) {
                unsigned idx = 0xFFFFFFFFu - (unsigned)(prev & 0xFFFFFFFFull);
                sy_s[k] = (float)(idx / NCLUS) / (float)NCLUS;
                sx_s[k] = (float)(idx % NCLUS) / (float)NCLUS;
            }
        }
    }
    __syncthreads();

    float inv_std = 1.0f / stdp[0];
    // Fy[b][h][k] -- k contiguous; loop ordered for coalesced writes.
    for (int t = tid; t < HH * NCLUS; t += 256) {
        int i = t / NCLUS;
        int k = t - i * NCLUS;
        float coord = (float)i / 224.0f;
        float ty = (coord - sy_s[k]) * inv_std;
        Fy[((size_t)b * HH + i) * NCLUS + k] = expf(0.5f * expf(-(ty * ty)));
    }
    // Fx[b][k][w] -- w contiguous.
    for (int t = tid; t < NCLUS * WW; t += 256) {
        int k = t / WW;
        int i = t - k * WW;
        float coord = (float)i / 224.0f;
        float tx = (coord - sx_s[k]) * inv_std;
        Fx[((size_t)b * NCLUS + k) * WW + i] = expf(0.5f * expf(-(tx * tx)));
    }
}

// ---------------------------------------------------------------------------
// Kernel C: out[b,k,h,w] = Fy[b,h,k]*Fx[b,k,w] / sum_k(...). Pure mul/fma +
// coalesced stores; HBM-write-bound. 448 threads = 7 full waves, 2 rows per
// block, zero idle lanes.
// ---------------------------------------------------------------------------
__global__ __launch_bounds__(448) void markers_kernel(
        const float* __restrict__ Fy, const float* __restrict__ Fx,
        float* __restrict__ out) {
    __shared__ float fy2[2 * NCLUS];
    int blk = blockIdx.x;
    int b = blk / 112;
    int h0 = (blk - b * 112) * 2;
    int tid = threadIdx.x;
    if (tid < 2 * NCLUS) fy2[tid] = Fy[((size_t)b * HH + h0) * NCLUS + tid];
    __syncthreads();

    int row = tid / 224;
    int w = tid - row * 224;
    const float* fyp = &fy2[row * NCLUS];
    const float* fxp = Fx + (size_t)b * NCLUS * WW + w;

    float p[NCLUS];
    float s0 = 0.f, s1 = 0.f, s2 = 0.f, s3 = 0.f;
#pragma unroll
    for (int k = 0; k < NCLUS; k += 4) {
        float a0 = fyp[k]     * fxp[(size_t)(k)     * WW];
        float a1 = fyp[k + 1] * fxp[(size_t)(k + 1) * WW];
        float a2 = fyp[k + 2] * fxp[(size_t)(k + 2) * WW];
        float a3 = fyp[k + 3] * fxp[(size_t)(k + 3) * WW];
        p[k] = a0; p[k + 1] = a1; p[k + 2] = a2; p[k + 3] = a3;
        s0 += a0; s1 += a1; s2 += a2; s3 += a3;
    }
    float r = 1.0f / ((s0 + s1) + (s2 + s3));
    int h = h0 + row;
    size_t base = (size_t)b * NCLUS * HW + (size_t)h * WW + w;
#pragma unroll
    for (int k = 0; k < NCLUS; ++k) {
        out[base + (size_t)k * HW] = p[k] * r;
    }
}

// ---------------------------------------------------------------------------
extern "C" void kernel_launch(void* const* d_in, const int* in_sizes, int n_in,
                              void* d_out, int out_size, void* d_ws,
                              size_t ws_size, hipStream_t stream) {
    const float* cf = (const float*)d_in[0];   // (32, 65, 224, 224) f32
    const float* stdp = (const float*)d_in[1]; // scalar f32
    float* out = (float*)d_out;                // (32, 56, 224, 224) f32

    char* ws = (char*)d_ws;
    float* pooled = (float*)ws;                              // 401 KB
    float* Fy = (float*)(ws + 512 * 1024);                   // 1.6 MB
    float* Fx = (float*)(ws + 512 * 1024 + 2 * 1024 * 1024); // 1.6 MB

    pool_kernel<<<BB * 14, 256, 0, stream>>>(cf, pooled);
    topk_tables_kernel<<<BB, 256, 0, stream>>>(pooled, stdp, Fy, Fx);
    markers_kernel<<<BB * 112, 448, 0, stream>>>(Fy, Fx, out);
}

// Round 3
// 116.379 us; speedup vs baseline: 1.4115x; 1.3722x over previous
//
#include <hip/hip_runtime.h>
#include <math.h>

#define NCLUS 56
#define HH 224
#define WW 224
#define BB 32
#define CELLS (NCLUS * NCLUS) /* 3136 */
#define HW (HH * WW)

// ---------------------------------------------------------------------------
// Kernel A: Sobel -> grad mag -> inverted -> 4x4 mean pool. (unchanged)
// ---------------------------------------------------------------------------
__global__ __launch_bounds__(256) void pool_kernel(const float* __restrict__ cf,
                                                   float* __restrict__ pooled) {
    __shared__ float lds[18][226];
    int b = blockIdx.x / 14;
    int grp = blockIdx.x - b * 14;
    int tid = threadIdx.x;
    const float* e = cf + ((size_t)b * 65 + 64) * HW;

    int y0 = grp * 16 - 1;
    for (int t = tid; t < 18 * 224; t += 256) {
        int r = t / 224;
        int c = t - r * 224;
        int y = y0 + r;
        lds[r][c + 1] = (y >= 0 && y < HH) ? e[y * WW + c] : 0.0f;
    }
    if (tid < 18) { lds[tid][0] = 0.0f; lds[tid][225] = 0.0f; }
    __syncthreads();

    if (tid >= 224) return;
    int lby = tid / 56;
    int bx = tid - lby * 56;
    int r0 = lby * 4;
    int c0 = bx * 4;

    float patch[6][6];
#pragma unroll
    for (int i = 0; i < 6; ++i)
#pragma unroll
        for (int j = 0; j < 6; ++j) patch[i][j] = lds[r0 + i][c0 + j];

    float s = 0.0f;
#pragma unroll
    for (int iy = 0; iy < 4; ++iy) {
#pragma unroll
        for (int ix = 0; ix < 4; ++ix) {
            float gx = (patch[iy][ix + 2] - patch[iy][ix])
                     + 2.0f * (patch[iy + 1][ix + 2] - patch[iy + 1][ix])
                     + (patch[iy + 2][ix + 2] - patch[iy + 2][ix]);
            float gy = (patch[iy + 2][ix] - patch[iy][ix])
                     + 2.0f * (patch[iy + 2][ix + 1] - patch[iy][ix + 1])
                     + (patch[iy + 2][ix + 2] - patch[iy][ix + 2]);
            float gm = sqrtf(gx * gx + gy * gy);
            s += 1.0f - 0.5f * gm;
        }
    }
    pooled[b * CELLS + (grp * 4 + lby) * NCLUS + bx] = s * 0.0625f;
}

// ---------------------------------------------------------------------------
// Kernel B: per-batch top-56 via RADIX SELECT + exp-factored tables.
// Wave 0 holds 49 transformed-float high-words per lane. Greedy MSB-first
// prefix refinement (branchless, butterfly popcount-sum per bit, early exit
// once candidate count <= 448) finds a threshold T with top-56 subset of
// {hi >= T}. Candidates are gathered to LDS, then rank-sorted by full u64
// key (value desc, lower index first -- exact jax.lax.top_k order) with all
// 256 threads. Replaces 56 serial dependent argmax rounds (~26us) with
// ~16 cheap bit rounds + one rank pass (~5us).
// ---------------------------------------------------------------------------
__global__ __launch_bounds__(256) void topk_tables_kernel(
        const float* __restrict__ pooled, const float* __restrict__ stdp,
        float* __restrict__ Fy, float* __restrict__ Fx) {
    int b = blockIdx.x;
    int tid = threadIdx.x;
    __shared__ unsigned long long list[CELLS]; // worst-case capacity
    __shared__ float sy_s[NCLUS], sx_s[NCLUS];
    __shared__ unsigned nlist_s;
    if (tid == 0) nlist_s = 0;  // wave0-internal ordering suffices

    if (tid < 64) {
        unsigned hi[49];
#pragma unroll
        for (int j = 0; j < 49; ++j) {
            int i = j * 64 + tid;
            unsigned u = __float_as_uint(pooled[b * CELLS + i]);
            hi[j] = (u & 0x80000000u) ? ~u : (u | 0x80000000u);
        }
        unsigned prefix = 0;
        unsigned cnt = CELLS;
        for (int bit = 31; bit >= 0; --bit) {
            if (cnt <= 448u) break;
            unsigned cand = prefix | (1u << bit);
            unsigned c = 0;
#pragma unroll
            for (int j = 0; j < 49; ++j) c += (hi[j] >= cand) ? 1u : 0u;
#pragma unroll
            for (int off = 32; off >= 1; off >>= 1)
                c += __shfl_xor(c, off, 64);
            if (c >= (unsigned)NCLUS) { prefix = cand; cnt = c; } // uniform
        }
#pragma unroll
        for (int j = 0; j < 49; ++j) {
            if (hi[j] >= prefix) {
                unsigned pos = atomicAdd(&nlist_s, 1u);
                unsigned i = (unsigned)(j * 64 + tid);
                list[pos] = ((unsigned long long)hi[j] << 32) |
                            (unsigned long long)(0xFFFFFFFFu - i);
            }
        }
    }
    __syncthreads();

    int N = (int)nlist_s;
    for (int c = tid; c < N; c += 256) {
        unsigned long long key = list[c];
        int r = 0;
        for (int j = 0; j < N; ++j) r += (list[j] > key) ? 1 : 0;
        if (r < NCLUS) {
            unsigned idx = 0xFFFFFFFFu - (unsigned)(key & 0xFFFFFFFFull);
            sy_s[r] = (float)(idx / NCLUS) / (float)NCLUS;
            sx_s[r] = (float)(idx % NCLUS) / (float)NCLUS;
        }
    }
    __syncthreads();

    float inv_std = 1.0f / stdp[0];
    for (int t = tid; t < HH * NCLUS; t += 256) {
        int i = t / NCLUS;
        int k = t - i * NCLUS;
        float coord = (float)i / 224.0f;
        float ty = (coord - sy_s[k]) * inv_std;
        Fy[((size_t)b * HH + i) * NCLUS + k] = expf(0.5f * expf(-(ty * ty)));
    }
    for (int t = tid; t < NCLUS * WW; t += 256) {
        int k = t / WW;
        int i = t - k * WW;
        float coord = (float)i / 224.0f;
        float tx = (coord - sx_s[k]) * inv_std;
        Fx[((size_t)b * NCLUS + k) * WW + i] = expf(0.5f * expf(-(tx * tx)));
    }
}

// ---------------------------------------------------------------------------
// Kernel C: out[b,k,h,w] = Fy[b,h,k]*Fx[b,k,w] / sum. TWO-PASS recompute:
// pass 1 accumulates the k-sum only, pass 2 recomputes fy*fx and stores --
// no p[56] register array (spill-proof, ~32 VGPRs), float4 loads/stores
// (896B contiguous per 56-lane group, 3.5x fewer store instructions).
// 448 threads = 8 rows x 56 float4-columns; grid 32*28.
// ---------------------------------------------------------------------------
__global__ __launch_bounds__(448) void markers_kernel(
        const float* __restrict__ Fy, const float* __restrict__ Fx,
        float* __restrict__ out) {
    __shared__ float fy_s[8 * NCLUS]; // 448
    int blk = blockIdx.x;
    int b = blk / 28;
    int h0 = (blk - b * 28) * 8;
    int tid = threadIdx.x;
    fy_s[tid] = Fy[((size_t)b * HH + h0) * NCLUS + tid];
    __syncthreads();

    int row = tid / 56;        // 0..7
    int wq = tid - row * 56;   // 0..55 -> w = 4*wq
    const float4* fx4 = (const float4*)(Fx + (size_t)b * NCLUS * WW) + wq;
    const float* fyp = fy_s + row * NCLUS;

    float sx = 0.f, sy = 0.f, sz = 0.f, sw = 0.f;
#pragma unroll 8
    for (int k = 0; k < NCLUS; ++k) {
        float fy = fyp[k];
        float4 fx = fx4[k * 56];
        sx = fmaf(fy, fx.x, sx);
        sy = fmaf(fy, fx.y, sy);
        sz = fmaf(fy, fx.z, sz);
        sw = fmaf(fy, fx.w, sw);
    }
    float rx = 1.0f / sx, ry = 1.0f / sy, rz = 1.0f / sz, rw = 1.0f / sw;

    float* op = out + (size_t)b * NCLUS * HW + (size_t)(h0 + row) * WW + wq * 4;
#pragma unroll 8
    for (int k = 0; k < NCLUS; ++k) {
        float fy = fyp[k];
        float4 fx = fx4[k * 56];
        float4 o;
        o.x = (fy * fx.x) * rx;
        o.y = (fy * fx.y) * ry;
        o.z = (fy * fx.z) * rz;
        o.w = (fy * fx.w) * rw;
        *(float4*)op = o;
        op += HW;
    }
}

// ---------------------------------------------------------------------------
extern "C" void kernel_launch(void* const* d_in, const int* in_sizes, int n_in,
                              void* d_out, int out_size, void* d_ws,
                              size_t ws_size, hipStream_t stream) {
    const float* cf = (const float*)d_in[0];   // (32, 65, 224, 224) f32
    const float* stdp = (const float*)d_in[1]; // scalar f32
    float* out = (float*)d_out;                // (32, 56, 224, 224) f32

    char* ws = (char*)d_ws;
    float* pooled = (float*)ws;                              // 401 KB
    float* Fy = (float*)(ws + 512 * 1024);                   // 1.6 MB
    float* Fx = (float*)(ws + 512 * 1024 + 2 * 1024 * 1024); // 1.6 MB

    pool_kernel<<<BB * 14, 256, 0, stream>>>(cf, pooled);
    topk_tables_kernel<<<BB, 256, 0, stream>>>(pooled, stdp, Fy, Fx);
    markers_kernel<<<BB * 28, 448, 0, stream>>>(Fy, Fx, out);
}

// Round 4
// 99.136 us; speedup vs baseline: 1.6570x; 1.1739x over previous
//
#include <hip/hip_runtime.h>
#include <math.h>

#define NCLUS 56
#define HH 224
#define WW 224
#define BB 32
#define CELLS (NCLUS * NCLUS) /* 3136 */
#define HW (HH * WW)

typedef float f32x4 __attribute__((ext_vector_type(4)));

// ---------------------------------------------------------------------------
// Kernel A: Sobel -> grad mag -> inverted -> 4x4 mean pool. (unchanged)
// ---------------------------------------------------------------------------
__global__ __launch_bounds__(256) void pool_kernel(const float* __restrict__ cf,
                                                   float* __restrict__ pooled) {
    __shared__ float lds[18][226];
    int b = blockIdx.x / 14;
    int grp = blockIdx.x - b * 14;
    int tid = threadIdx.x;
    const float* e = cf + ((size_t)b * 65 + 64) * HW;

    int y0 = grp * 16 - 1;
    for (int t = tid; t < 18 * 224; t += 256) {
        int r = t / 224;
        int c = t - r * 224;
        int y = y0 + r;
        lds[r][c + 1] = (y >= 0 && y < HH) ? e[y * WW + c] : 0.0f;
    }
    if (tid < 18) { lds[tid][0] = 0.0f; lds[tid][225] = 0.0f; }
    __syncthreads();

    if (tid >= 224) return;
    int lby = tid / 56;
    int bx = tid - lby * 56;
    int r0 = lby * 4;
    int c0 = bx * 4;

    float patch[6][6];
#pragma unroll
    for (int i = 0; i < 6; ++i)
#pragma unroll
        for (int j = 0; j < 6; ++j) patch[i][j] = lds[r0 + i][c0 + j];

    float s = 0.0f;
#pragma unroll
    for (int iy = 0; iy < 4; ++iy) {
#pragma unroll
        for (int ix = 0; ix < 4; ++ix) {
            float gx = (patch[iy][ix + 2] - patch[iy][ix])
                     + 2.0f * (patch[iy + 1][ix + 2] - patch[iy + 1][ix])
                     + (patch[iy + 2][ix + 2] - patch[iy + 2][ix]);
            float gy = (patch[iy + 2][ix] - patch[iy][ix])
                     + 2.0f * (patch[iy + 2][ix + 1] - patch[iy][ix + 1])
                     + (patch[iy + 2][ix + 2] - patch[iy][ix + 2]);
            float gm = sqrtf(gx * gx + gy * gy);
            s += 1.0f - 0.5f * gm;
        }
    }
    pooled[b * CELLS + (grp * 4 + lby) * NCLUS + bx] = s * 0.0625f;
}

// ---------------------------------------------------------------------------
// Kernel B: per-batch top-56 via radix select + rank sort. Outputs ONLY the
// normalized seed coords sy[b][k], sx[b][k] (exact jax.lax.top_k order:
// value descending, lower index wins ties).
// ---------------------------------------------------------------------------
__global__ __launch_bounds__(256) void topk_kernel(
        const float* __restrict__ pooled,
        float* __restrict__ sy, float* __restrict__ sx) {
    int b = blockIdx.x;
    int tid = threadIdx.x;
    __shared__ unsigned long long list[CELLS];
    __shared__ unsigned nlist_s;
    if (tid == 0) nlist_s = 0;

    if (tid < 64) {
        unsigned hi[49];
#pragma unroll
        for (int j = 0; j < 49; ++j) {
            int i = j * 64 + tid;
            unsigned u = __float_as_uint(pooled[b * CELLS + i]);
            hi[j] = (u & 0x80000000u) ? ~u : (u | 0x80000000u);
        }
        unsigned prefix = 0;
        unsigned cnt = CELLS;
        for (int bit = 31; bit >= 0; --bit) {
            if (cnt <= 448u) break;
            unsigned cand = prefix | (1u << bit);
            unsigned c = 0;
#pragma unroll
            for (int j = 0; j < 49; ++j) c += (hi[j] >= cand) ? 1u : 0u;
#pragma unroll
            for (int off = 32; off >= 1; off >>= 1)
                c += __shfl_xor(c, off, 64);
            if (c >= (unsigned)NCLUS) { prefix = cand; cnt = c; } // uniform
        }
#pragma unroll
        for (int j = 0; j < 49; ++j) {
            if (hi[j] >= prefix) {
                unsigned pos = atomicAdd(&nlist_s, 1u);
                unsigned i = (unsigned)(j * 64 + tid);
                list[pos] = ((unsigned long long)hi[j] << 32) |
                            (unsigned long long)(0xFFFFFFFFu - i);
            }
        }
    }
    __syncthreads();

    int N = (int)nlist_s;
    for (int c = tid; c < N; c += 256) {
        unsigned long long key = list[c];
        int r = 0;
        for (int j = 0; j < N; ++j) r += (list[j] > key) ? 1 : 0;
        if (r < NCLUS) {
            unsigned idx = 0xFFFFFFFFu - (unsigned)(key & 0xFFFFFFFFull);
            sy[b * NCLUS + r] = (float)(idx / NCLUS) / (float)NCLUS;
            sx[b * NCLUS + r] = (float)(idx % NCLUS) / (float)NCLUS;
        }
    }
}

// ---------------------------------------------------------------------------
// Kernel C: fused tables + factored softmax + NT stores.
// Per block (b, 8 rows): build Fx[b] (56x224, 50KB) in LDS and fy (8x56)
// from sy/sx -- all exp work stays on-chip, so the 360MB store stream can't
// evict anything we re-read (the round-3 suspect). Two-pass recompute from
// LDS, float4 everywhere, nontemporal stores. 52KB LDS -> 3 blocks/CU.
// ---------------------------------------------------------------------------
__global__ __launch_bounds__(448) void markers_kernel(
        const float* __restrict__ sy, const float* __restrict__ sx,
        const float* __restrict__ stdp, float* __restrict__ out) {
    __shared__ float fx_lds[NCLUS][WW]; // 50,176 B
    __shared__ float fy_s[8 * NCLUS];   //  1,792 B
    int blk = blockIdx.x;
    int b = blk / 28;
    int h0 = (blk - b * 28) * 8;
    int tid = threadIdx.x;
    float inv_std = 1.0f / stdp[0];
    const float* syb = sy + b * NCLUS;
    const float* sxb = sx + b * NCLUS;

    // Fx table: 12544 entries = 28 per thread, w-contiguous LDS writes.
    for (int t = tid; t < NCLUS * WW; t += 448) {
        int k = t / WW;
        int w = t - k * WW;
        float tx = ((float)w / 224.0f - sxb[k]) * inv_std;
        fx_lds[k][w] = expf(0.5f * expf(-(tx * tx)));
    }
    // fy: exactly one entry per thread (448 = 8 rows x 56 k).
    {
        int row = tid / NCLUS;
        int k = tid - row * NCLUS;
        float ty = ((float)(h0 + row) / 224.0f - syb[k]) * inv_std;
        fy_s[tid] = expf(0.5f * expf(-(ty * ty)));
    }
    __syncthreads();

    int row = tid / 56;      // 0..7
    int wq = tid - row * 56; // 0..55 -> w = 4*wq
    const float* fyp = fy_s + row * NCLUS;

    float s0 = 0.f, s1 = 0.f, s2 = 0.f, s3 = 0.f;
#pragma unroll 8
    for (int k = 0; k < NCLUS; ++k) {
        float fy = fyp[k];
        f32x4 fx = *(const f32x4*)&fx_lds[k][wq * 4];
        s0 = fmaf(fy, fx.x, s0);
        s1 = fmaf(fy, fx.y, s1);
        s2 = fmaf(fy, fx.z, s2);
        s3 = fmaf(fy, fx.w, s3);
    }
    float r0 = 1.0f / s0, r1 = 1.0f / s1, r2 = 1.0f / s2, r3 = 1.0f / s3;

    float* op = out + (size_t)b * NCLUS * HW + (size_t)(h0 + row) * WW + wq * 4;
#pragma unroll 8
    for (int k = 0; k < NCLUS; ++k) {
        float fy = fyp[k];
        f32x4 fx = *(const f32x4*)&fx_lds[k][wq * 4];
        f32x4 o;
        o.x = (fy * fx.x) * r0;
        o.y = (fy * fx.y) * r1;
        o.z = (fy * fx.z) * r2;
        o.w = (fy * fx.w) * r3;
        __builtin_nontemporal_store(o, (f32x4*)op);
        op += HW;
    }
}

// ---------------------------------------------------------------------------
extern "C" void kernel_launch(void* const* d_in, const int* in_sizes, int n_in,
                              void* d_out, int out_size, void* d_ws,
                              size_t ws_size, hipStream_t stream) {
    const float* cf = (const float*)d_in[0];   // (32, 65, 224, 224) f32
    const float* stdp = (const float*)d_in[1]; // scalar f32
    float* out = (float*)d_out;                // (32, 56, 224, 224) f32

    char* ws = (char*)d_ws;
    float* pooled = (float*)ws;                    // 401 KB
    float* sy = (float*)(ws + 512 * 1024);         // 7 KB
    float* sx = (float*)(ws + 576 * 1024);         // 7 KB

    pool_kernel<<<BB * 14, 256, 0, stream>>>(cf, pooled);
    topk_kernel<<<BB, 256, 0, stream>>>(pooled, sy, sx);
    markers_kernel<<<BB * 28, 448, 0, stream>>>(sy, sx, stdp, out);
}